// Round 3
// baseline (75.672 us; speedup 1.0000x reference)
//
#include <hip/hip_runtime.h>
#include <hip/hip_bf16.h>

typedef short bfrag8 __attribute__((ext_vector_type(8)));
typedef float f32x4v __attribute__((ext_vector_type(4)));
typedef unsigned short U16;
typedef unsigned int U32;

#define NN 4096
#define DD 128

static __device__ __forceinline__ U16 f2bf(float f){
  union { __hip_bfloat16 b; U16 u; } cv;
  cv.b = __float2bfloat16(f);
  return cv.u;
}

static __device__ __forceinline__ float bf2f(U16 u){
  union { float f; U32 u; } cv;
  cv.u = ((U32)u) << 16;
  return cv.f;
}

// async global->LDS, 16B per lane: lds dest = wave-uniform base + lane*16,
// global src = per-lane address.
#define GLL16(gsrc, ldst) \
  __builtin_amdgcn_global_load_lds((const __attribute__((address_space(1))) unsigned int*)(gsrc), \
                                   (__attribute__((address_space(3))) unsigned int*)(ldst), 16, 0, 0)

// ---------------- fused pre-pass ----------------
// blocks [0,256): k1 — x2 = x*(nw+1)+nb; h = LN(x2@W); writes h_lnB (bf16),
//                 hTt (bf16 tiled+inverse-swizzled), f1/f2.
// blocks [256,2304): pack adj (int 0/1) into 64-bit masks (ballot).
__global__ __launch_bounds__(256) void kA_prep(
    const float* __restrict__ x, const float* __restrict__ W,
    const int* __restrict__ adj,
    const float* __restrict__ nw, const float* __restrict__ nb,
    const float* __restrict__ gamma, const float* __restrict__ beta,
    const float* __restrict__ a1, const float* __restrict__ a2,
    U16* __restrict__ h_lnB, U16* __restrict__ hTt,
    float* __restrict__ f1, float* __restrict__ f2,
    unsigned long long* __restrict__ adjb64)
{
  __shared__ U16 lds[16384];                 // 32 KB: W^T (swizzled), later hb[64][128]
  const int tid = threadIdx.x;
  const int lane = tid & 63, w = tid >> 6;

  if (blockIdx.x >= 256){
    // ---------- adj pack ----------
    const int Wv = (blockIdx.x - 256)*4 + w;   // wave id, 8192 total
    const int* src = adj + (size_t)Wv*2048;
    unsigned long long* dst = adjb64 + (size_t)Wv*32;
    #pragma unroll 4
    for (int p = 0; p < 32; ++p){
      int v = src[p*64 + lane];
      unsigned long long m = __ballot(v != 0);
      if (lane == 0) dst[p] = m;
    }
    return;
  }

  const int l15 = lane & 15, grp = lane >> 4;

  // ---------- load W (f32 [d][dp]) -> LDS bf16 transposed [dp][d] swizzled ----------
  #pragma unroll
  for (int q = 0; q < 16; ++q){
    int idx4 = q*256 + tid;                  // float4 index
    int d = idx4 >> 5, dp = (idx4 & 31)*4;
    float4 v = *reinterpret_cast<const float4*>(W + idx4*4);
    float vv[4] = {v.x, v.y, v.z, v.w};
    #pragma unroll
    for (int e = 0; e < 4; ++e){
      int dpe = dp + e;
      lds[dpe*128 + ((d & ~7) ^ ((dpe & 15) << 3)) + (d & 7)] = f2bf(vv[e]);
    }
  }
  __syncthreads();

  const int rA = blockIdx.x*64 + w*16 + l15;
  const int nA = rA & 4095;
  const float wgt = nw[nA] + 1.0f, bia = nb[nA];
  const float* xr = x + (size_t)rA*DD;

  f32x4v acc[8] = {};
  #pragma unroll
  for (int ks = 0; ks < 4; ++ks){
    int d8 = ks*32 + grp*8;
    float4 xa = *reinterpret_cast<const float4*>(xr + d8);
    float4 xb = *reinterpret_cast<const float4*>(xr + d8 + 4);
    bfrag8 af;
    af[0] = (short)f2bf(xa.x*wgt + bia);
    af[1] = (short)f2bf(xa.y*wgt + bia);
    af[2] = (short)f2bf(xa.z*wgt + bia);
    af[3] = (short)f2bf(xa.w*wgt + bia);
    af[4] = (short)f2bf(xb.x*wgt + bia);
    af[5] = (short)f2bf(xb.y*wgt + bia);
    af[6] = (short)f2bf(xb.z*wgt + bia);
    af[7] = (short)f2bf(xb.w*wgt + bia);
    #pragma unroll
    for (int nf = 0; nf < 8; ++nf){
      int dp = nf*16 + l15;
      bfrag8 bf = *reinterpret_cast<const bfrag8*>(
          lds + dp*128 + ((((ks*4 + grp)*8)) ^ ((dp&15)<<3)));
      acc[nf] = __builtin_amdgcn_mfma_f32_16x16x32_bf16(af, bf, acc[nf], 0, 0, 0);
    }
  }

  float gc[8], bc[8], c1[8], c2[8];
  #pragma unroll
  for (int nf = 0; nf < 8; ++nf){
    int col = nf*16 + l15;
    gc[nf] = gamma[col]; bc[nf] = beta[col];
    c1[nf] = a1[col];    c2[nf] = a2[col];
  }

  // C/D layout: col = lane&15, row = (lane>>4)*4 + r   (m89-verified)
  const int rCb = blockIdx.x*64 + w*16 + grp*4;
  #pragma unroll
  for (int r = 0; r < 4; ++r){
    float s = 0.f, qq = 0.f;
    #pragma unroll
    for (int nf = 0; nf < 8; ++nf){ float v = acc[nf][r]; s += v; qq += v*v; }
    #pragma unroll
    for (int m = 1; m < 16; m <<= 1){ s += __shfl_xor(s, m); qq += __shfl_xor(qq, m); }
    float mu = s * 0.0078125f;
    float var = fmaxf(qq*0.0078125f - mu*mu, 0.f);
    float rstd = rsqrtf(var + 1e-5f);
    const int rC = rCb + r;
    float p1 = 0.f, p2 = 0.f;
    #pragma unroll
    for (int nf = 0; nf < 8; ++nf){
      float hn = (acc[nf][r] - mu)*rstd*gc[nf] + bc[nf];
      acc[nf][r] = hn;
      h_lnB[(size_t)rC*DD + nf*16 + l15] = f2bf(hn);
      p1 += hn*c1[nf]; p2 += hn*c2[nf];
    }
    #pragma unroll
    for (int m = 1; m < 16; m <<= 1){ p1 += __shfl_xor(p1, m); p2 += __shfl_xor(p2, m); }
    if (l15 == 0){ f1[rC] = p1; f2[rC] = p2; }
  }

  __syncthreads();   // W^T no longer needed; reuse LDS as hb[64 n][128 d]
  #pragma unroll
  for (int r = 0; r < 4; ++r)
    #pragma unroll
    for (int nf = 0; nf < 8; ++nf)
      lds[(w*16 + grp*4 + r)*128 + nf*16 + l15] = f2bf(acc[nf][r]);
  __syncthreads();

  // tiled + inverse-swizzled write: chunk (d,qc) holds h[n=(qc^(d&7))*8+e][d],
  // so k2 stages linearly (global_load_lds) and reads with the XOR swizzle.
  {
    const int r0 = blockIdx.x*64;
    const int tilei = (r0 >> 12)*64 + ((r0 >> 6) & 63);
    U16* dstt = hTt + (size_t)tilei*8192;
    #pragma unroll
    for (int k = 0; k < 4; ++k){
      int cid = tid*4 + k;             // 0..1023
      int d = cid >> 3, qc = cid & 7;
      int nl = (qc ^ (d & 7)) * 8;
      bfrag8 t;
      #pragma unroll
      for (int e = 0; e < 8; ++e)
        t[e] = (short)lds[(nl + e)*128 + d];
      *reinterpret_cast<bfrag8*>(dstt + d*64 + qc*8) = t;
    }
  }
}

// ---------------- kernel 2: fused att-gen + att@h + elu + residual ----------------
// grid 256: block = (batch b, 64 i-rows); 16 waves = 4 tiles(16 rows) x 4 K-quarters.
// B-tiles staged via global_load_lds from tiled hTt, double-buffered 128KB LDS.
__global__ __launch_bounds__(1024) void k2_main(
    const U32* __restrict__ adjb, const U16* __restrict__ hTt,
    const float* __restrict__ f1, const float* __restrict__ f2,
    const U16* __restrict__ h_lnB, float* __restrict__ out)
{
  __shared__ U16 bt[65536];                  // 128 KB: [buf 2][kq 4][8192]
  const int tid = threadIdx.x;
  const int lane = tid & 63, w = tid >> 6;
  const int kq = w & 3, tile = w >> 2;
  const int l15 = lane & 15, grp = lane >> 4;
  const int b = blockIdx.x >> 6;
  const int i0 = (blockIdx.x & 63)*64 + tile*16;
  const int row = i0 + l15;

  const float CMASK = 0.2f * -9.0e15f;       // leaky(MASK_VAL), exact
  const float A2C   = 0.04f;                 // leaky∘leaky negative slope

  const float f1v = f1[b*NN + row];
  const float* f2b = f2 + b*NN;
  const U32* arow = adjb + (size_t)row*128;
  const U16* hTb = hTt + (size_t)b*64*8192;

  // staging: wave w stages quarter kq's sub-block sub = tile (4KB = 4 x GLL16)
  const int sub = tile;
  const U16* sbase = hTb + (size_t)kq*16*8192 + sub*2048 + lane*8;

  // prologue: stage s=0 into buf 0
  {
    int dsto = kq*8192 + sub*2048;
    #pragma unroll
    for (int c = 0; c < 4; ++c)
      GLL16(sbase + c*512, &bt[dsto + c*512]);
  }
  // prologue: regs for s=0
  float4 cfa0, cfb0, cfa1, cfb1; U32 cw0, cw1;
  {
    int j0 = kq*1024 + grp*8;
    cfa0 = *reinterpret_cast<const float4*>(f2b + j0);
    cfb0 = *reinterpret_cast<const float4*>(f2b + j0 + 4);
    cfa1 = *reinterpret_cast<const float4*>(f2b + j0 + 32);
    cfb1 = *reinterpret_cast<const float4*>(f2b + j0 + 36);
    cw0 = arow[kq*32];
    cw1 = arow[kq*32 + 1];
  }

  f32x4v acc[8] = {};
  __syncthreads();                            // tile 0 staged

  for (int s = 0; s < 16; ++s){
    if (s < 15){                              // issue next tile's staging first
      const U16* gp = sbase + (size_t)(s+1)*8192;
      int dsto = (((s+1)&1)*4 + kq)*8192 + sub*2048;
      #pragma unroll
      for (int c = 0; c < 4; ++c)
        GLL16(gp + c*512, &bt[dsto + c*512]);
    }
    float4 nfa0, nfb0, nfa1, nfb1; U32 nw0, nw1;
    if (s < 15){                              // prefetch next iter's f2 / adj bits
      int j0 = kq*1024 + (s+1)*64 + grp*8;
      nfa0 = *reinterpret_cast<const float4*>(f2b + j0);
      nfb0 = *reinterpret_cast<const float4*>(f2b + j0 + 4);
      nfa1 = *reinterpret_cast<const float4*>(f2b + j0 + 32);
      nfb1 = *reinterpret_cast<const float4*>(f2b + j0 + 36);
      int wi = kq*32 + (s+1)*2;
      nw0 = arow[wi]; nw1 = arow[wi+1];
    }

    const int bbase = ((s&1)*4 + kq)*8192;
    // ---- kc = 0 ----
    {
      U32 byt = (cw0 >> (grp*8)) & 0xffu;
      bfrag8 af;
      float sv, uv;
      sv = f1v + cfa0.x; uv = fmaxf(sv, A2C*sv); af[0] = (short)f2bf((byt & 1u)  ? uv : CMASK);
      sv = f1v + cfa0.y; uv = fmaxf(sv, A2C*sv); af[1] = (short)f2bf((byt & 2u)  ? uv : CMASK);
      sv = f1v + cfa0.z; uv = fmaxf(sv, A2C*sv); af[2] = (short)f2bf((byt & 4u)  ? uv : CMASK);
      sv = f1v + cfa0.w; uv = fmaxf(sv, A2C*sv); af[3] = (short)f2bf((byt & 8u)  ? uv : CMASK);
      sv = f1v + cfb0.x; uv = fmaxf(sv, A2C*sv); af[4] = (short)f2bf((byt & 16u) ? uv : CMASK);
      sv = f1v + cfb0.y; uv = fmaxf(sv, A2C*sv); af[5] = (short)f2bf((byt & 32u) ? uv : CMASK);
      sv = f1v + cfb0.z; uv = fmaxf(sv, A2C*sv); af[6] = (short)f2bf((byt & 64u) ? uv : CMASK);
      sv = f1v + cfb0.w; uv = fmaxf(sv, A2C*sv); af[7] = (short)f2bf((byt & 128u)? uv : CMASK);
      const int cr8 = grp*8;
      #pragma unroll
      for (int nf = 0; nf < 8; ++nf){
        int d = nf*16 + l15;
        bfrag8 bf = *reinterpret_cast<const bfrag8*>(
            bt + bbase + d*64 + (cr8 ^ ((d&7)<<3)));
        acc[nf] = __builtin_amdgcn_mfma_f32_16x16x32_bf16(af, bf, acc[nf], 0, 0, 0);
      }
    }
    // ---- kc = 1 ----
    {
      U32 byt = (cw1 >> (grp*8)) & 0xffu;
      bfrag8 af;
      float sv, uv;
      sv = f1v + cfa1.x; uv = fmaxf(sv, A2C*sv); af[0] = (short)f2bf((byt & 1u)  ? uv : CMASK);
      sv = f1v + cfa1.y; uv = fmaxf(sv, A2C*sv); af[1] = (short)f2bf((byt & 2u)  ? uv : CMASK);
      sv = f1v + cfa1.z; uv = fmaxf(sv, A2C*sv); af[2] = (short)f2bf((byt & 4u)  ? uv : CMASK);
      sv = f1v + cfa1.w; uv = fmaxf(sv, A2C*sv); af[3] = (short)f2bf((byt & 8u)  ? uv : CMASK);
      sv = f1v + cfb1.x; uv = fmaxf(sv, A2C*sv); af[4] = (short)f2bf((byt & 16u) ? uv : CMASK);
      sv = f1v + cfb1.y; uv = fmaxf(sv, A2C*sv); af[5] = (short)f2bf((byt & 32u) ? uv : CMASK);
      sv = f1v + cfb1.z; uv = fmaxf(sv, A2C*sv); af[6] = (short)f2bf((byt & 64u) ? uv : CMASK);
      sv = f1v + cfb1.w; uv = fmaxf(sv, A2C*sv); af[7] = (short)f2bf((byt & 128u)? uv : CMASK);
      const int cr8 = 32 + grp*8;
      #pragma unroll
      for (int nf = 0; nf < 8; ++nf){
        int d = nf*16 + l15;
        bfrag8 bf = *reinterpret_cast<const bfrag8*>(
            bt + bbase + d*64 + (cr8 ^ ((d&7)<<3)));
        acc[nf] = __builtin_amdgcn_mfma_f32_16x16x32_bf16(af, bf, acc[nf], 0, 0, 0);
      }
    }

    __syncthreads();   // all waves done with buf[s&1]; next staging drained here
    cfa0 = nfa0; cfb0 = nfb0; cfa1 = nfa1; cfb1 = nfb1; cw0 = nw0; cw1 = nw1;
  }

  // combine 4 K-quarters through LDS (reuse bt as f32 scratch), fused epilogue
  float* sc = reinterpret_cast<float*>(bt);   // 3 regions x 8192 f32
  if (kq != 0){
    int rbase = (kq-1)*8192 + tile*2048;
    #pragma unroll
    for (int nf = 0; nf < 8; ++nf)
      #pragma unroll
      for (int r = 0; r < 4; ++r)
        sc[rbase + (grp*4 + r)*128 + nf*16 + l15] = acc[nf][r];
  }
  __syncthreads();
  if (kq == 0){
    #pragma unroll
    for (int nf = 0; nf < 8; ++nf)
      #pragma unroll
      for (int r = 0; r < 4; ++r){
        int off = tile*2048 + (grp*4 + r)*128 + nf*16 + l15;
        float hp = acc[nf][r] + sc[off] + sc[8192 + off] + sc[16384 + off];
        float e = hp > 0.f ? hp : __expf(hp) - 1.f;
        size_t o = ((size_t)b*NN + i0 + grp*4 + r)*DD + nf*16 + l15;
        out[o] = e + bf2f(h_lnB[o]);
      }
  }
}

extern "C" void kernel_launch(void* const* d_in, const int* in_sizes, int n_in,
                              void* d_out, int out_size, void* d_ws, size_t ws_size,
                              hipStream_t stream) {
  const float* x     = (const float*)d_in[0];
  const int*   adj   = (const int*)  d_in[1];
  const float* W     = (const float*)d_in[2];
  const float* a1    = (const float*)d_in[3];
  const float* a2    = (const float*)d_in[4];
  const float* nw    = (const float*)d_in[5];
  const float* nb    = (const float*)d_in[6];
  const float* gamma = (const float*)d_in[7];
  const float* beta  = (const float*)d_in[8];
  float* out = (float*)d_out;

  char* ws = (char*)d_ws;
  U16*   h_lnB = (U16*)(ws);                            // 4 MB
  U16*   hTt   = (U16*)(ws + 4*1024*1024);              // 4 MB (tiled)
  float* f1    = (float*)(ws + 8*1024*1024);            // 64 KB
  float* f2    = (float*)(ws + 8*1024*1024 + 64*1024);  // 64 KB
  unsigned long long* adjb64 = (unsigned long long*)(ws + 9*1024*1024); // 2 MB

  kA_prep<<<dim3(2304), dim3(256), 0, stream>>>(x, W, adj, nw, nb, gamma, beta,
                                                a1, a2, h_lnB, hTt, f1, f2, adjb64);
  k2_main<<<dim3(256),  dim3(1024), 0, stream>>>((const U32*)adjb64, hTt, f1, f2,
                                                 h_lnB, out);
}